// Round 1
// baseline (169.435 us; speedup 1.0000x reference)
//
#include <hip/hip_runtime.h>
#include <hip/hip_bf16.h>

// Fused MHA fwd: out = softmax(scale*Q@K^T + bias) @ V
// B=2 H=16 S=2048 D=64, fp32 in/out, bf16 MFMA.
// R3: XOR-swizzled LDS layouts, fused prep kernel.
// R4: software pipeline depth 1 — double-buffered K/V LDS, stage(t+1) issued
//     before compute(t), ONE barrier per tile (was 2, with vmcnt(0) drain
//     BEFORE compute -> every tile paid full memory latency serially).
//     Bias register-prefetched one tile ahead. LOG2E folded into Q scale and
//     bias init so softmax is exp2(sacc) directly.
//     LDS 24->40KB is free: grid (1024 blocks) caps us at 4 blocks/CU anyway.

#define SEQ 2048
#define DH  64
#define BHN 32
#define NTILE (SEQ / 64)
#define LOG2E 1.44269504088896f

typedef __attribute__((ext_vector_type(8))) short bf16x8;
typedef __attribute__((ext_vector_type(4))) float f32x4;
typedef __attribute__((ext_vector_type(8))) short short8v;

__device__ inline short f2b(float x) {
    union { float f; unsigned u; } v; v.f = x;
    unsigned r = v.u + 0x7fff + ((v.u >> 16) & 1);
    return (short)(r >> 16);
}

__device__ inline void gl_lds16(const void* g, void* l) {
    __builtin_amdgcn_global_load_lds(
        (const __attribute__((address_space(1))) void*)g,
        (__attribute__((address_space(3))) void*)l, 16, 0, 0);
}

// ---- fused prep: K fp32->bf16 (same layout) + V fp32->bf16 transposed ----
__global__ __launch_bounds__(256)
void prep_kv(const float* __restrict__ K, const float* __restrict__ V,
             short* __restrict__ Kb, short* __restrict__ Vt) {
    __shared__ short t[64 * 72];
    const int tid = threadIdx.x;
    const int bh = blockIdx.x >> 5, st = blockIdx.x & 31, s0 = st * 64;

    // K: straight convert, 64 rows x 64 cols
    {
        const float* Kp = K + ((size_t)bh * SEQ + s0) * DH;
        short* Ko = Kb + ((size_t)bh * SEQ + s0) * DH;
        #pragma unroll
        for (int i = 0; i < 2; ++i) {
            size_t o = (size_t)(tid + i * 256) * 8;
            f32x4 a = *(const f32x4*)(Kp + o);
            f32x4 b = *(const f32x4*)(Kp + o + 4);
            short8v s;
            #pragma unroll
            for (int j = 0; j < 4; ++j) { s[j] = f2b(a[j]); s[4 + j] = f2b(b[j]); }
            *(short8v*)(Ko + o) = s;
        }
    }

    // V: convert + transpose via LDS (padded stride 72 here; plain ds ops)
    const float* Vb = V + (size_t)bh * SEQ * DH + (size_t)s0 * DH;
    #pragma unroll
    for (int i = 0; i < 4; ++i) {
        int c = tid + i * 256, s = c >> 4, c4 = c & 15;
        f32x4 v = *(const f32x4*)(Vb + s * DH + c4 * 4);
        #pragma unroll
        for (int j = 0; j < 4; ++j) t[s * 72 + c4 * 4 + j] = f2b(v[j]);
    }
    __syncthreads();
    const int d = tid >> 2, part = tid & 3;
    short8v lo, hi;
    #pragma unroll
    for (int j = 0; j < 8; ++j) {
        lo[j] = t[(part * 16 + j) * 72 + d];
        hi[j] = t[(part * 16 + 8 + j) * 72 + d];
    }
    short* outp = Vt + (size_t)bh * DH * SEQ + (size_t)d * SEQ + s0 + part * 16;
    *(short8v*)outp = lo;
    *(short8v*)(outp + 8) = hi;
}

// ---- main fused attention ----
// LDS layouts XOR-swizzled (logical chunk c of row r lives at physical c^(r&7);
// staging fetches global chunk c^(r&7) into physical chunk c, reads use
// index (c ^ (r&7))). All LDS accesses <=2-way.
__global__ __launch_bounds__(256, 4)
void mha_main(const float* __restrict__ Q, const float* __restrict__ Bias,
              const short* __restrict__ Kb, const short* __restrict__ Vt,
              float* __restrict__ Out)
{
    __shared__ short lds_k[2][64 * DH];   // K tile [n][d], swizzled, dbuf
    __shared__ short lds_v[2][64 * DH];   // Vt tile [d][n], swizzled, dbuf
    __shared__ short lds_p[4 * 16 * 64];  // per-wave P [m][n], swizzled

    const int tid = threadIdx.x, lane = tid & 63, wave = tid >> 6;
    const int l15 = lane & 15, l4 = lane >> 4;
    const int qb = blockIdx.x & 31, bh = blockIdx.x >> 5;
    const int q0 = qb * 64;

    const float* Qb = Q + (size_t)bh * SEQ * DH;
    const short* Kh = Kb + (size_t)bh * SEQ * DH;
    const short* Vh = Vt + (size_t)bh * DH * SEQ;
    float* Ob = Out + (size_t)bh * SEQ * DH;

    // Q fragments (A-layout: m=l15, k=ks*32+l4*8+j), pre-scaled by LOG2E/8
    bf16x8 qf[2];
    {
        const float* qp = Qb + (size_t)(q0 + wave * 16 + l15) * DH;
        const float qs = 0.125f * LOG2E;
        #pragma unroll
        for (int ks = 0; ks < 2; ++ks) {
            short tmp[8];
            #pragma unroll
            for (int j = 0; j < 8; ++j) tmp[j] = f2b(qp[ks * 32 + l4 * 8 + j] * qs);
            qf[ks] = *reinterpret_cast<bf16x8*>(tmp);
        }
    }

    f32x4 o_acc[4];
    #pragma unroll
    for (int dt = 0; dt < 4; ++dt) o_acc[dt] = f32x4{0.f, 0.f, 0.f, 0.f};
    float l_part[4] = {0.f, 0.f, 0.f, 0.f};

    // staging: lane's LDS slot fixed (base + lane*16B); fetch swizzled global
    // chunk so LDS physical chunk c holds global chunk c^(row&7).
    const short* kg[2]; const short* vg[2]; short* kl[2]; short* vl[2];
    #pragma unroll
    for (int p = 0; p < 2; ++p) {
        int slot = p * 256 + wave * 64 + lane;   // 0..511
        int r_ = slot >> 3;                      // row 0..63
        int c_ = slot & 7;                       // physical 16B chunk
        int cg = c_ ^ (r_ & 7);                  // global chunk to fetch
        kg[p] = Kh + (size_t)r_ * DH + cg * 8;
        vg[p] = Vh + (size_t)r_ * SEQ + cg * 8;
        kl[p] = &lds_k[0][(size_t)(p * 256 + wave * 64) * 8];
        vl[p] = &lds_v[0][(size_t)(p * 256 + wave * 64) * 8];
    }
    const float* bp0 = Bias + (size_t)(q0 + wave * 16 + l4 * 4) * SEQ + l15;
    short* pw = &lds_p[wave * 16 * 64];
    const int swz = l15 & 7;                     // read-side XOR

    // ---- prologue: stage tile 0, prefetch bias 0 ----
    gl_lds16(kg[0], kl[0]);
    gl_lds16(kg[1], kl[1]);
    gl_lds16(vg[0], vl[0]);
    gl_lds16(vg[1], vl[1]);

    float bpre[4][4];                            // [nt][r], tile kt+1
    #pragma unroll
    for (int nt = 0; nt < 4; ++nt)
        #pragma unroll
        for (int r = 0; r < 4; ++r)
            bpre[nt][r] = bp0[(size_t)r * SEQ + nt * 16];

    __syncthreads();                             // tile 0 staged (vmcnt drain)

    for (int kt = 0; kt < NTILE; ++kt) {
        const int cur = kt & 1;
        const int nb = cur ^ 1;

        // issue next tile's stage FIRST: lands during this tile's compute.
        // buf[nb] was last read in iter kt-1; end-of-(kt-1) barrier protects.
        if (kt + 1 < NTILE) {
            const size_t koff = (size_t)(kt + 1) * 64 * DH;
            const int voff = (kt + 1) * 64;
            const int lo = nb * (64 * DH);
            gl_lds16(kg[0] + koff, kl[0] + lo);
            gl_lds16(kg[1] + koff, kl[1] + lo);
            gl_lds16(vg[0] + voff, vl[0] + lo);
            gl_lds16(vg[1] + voff, vl[1] + lo);
        }

        // consume prefetched bias -> MFMA C init (row=l4*4+r, col=nt*16+l15),
        // folding the LOG2E softmax factor here (Q already carries it).
        f32x4 sacc[4];
        #pragma unroll
        for (int nt = 0; nt < 4; ++nt)
            #pragma unroll
            for (int r = 0; r < 4; ++r)
                sacc[nt][r] = bpre[nt][r] * LOG2E;

        // issue next tile's bias loads; consumed next iteration
        if (kt + 1 < NTILE) {
            const float* bp = bp0 + (kt + 1) * 64;
            #pragma unroll
            for (int nt = 0; nt < 4; ++nt)
                #pragma unroll
                for (int r = 0; r < 4; ++r)
                    bpre[nt][r] = bp[(size_t)r * SEQ + nt * 16];
        }

        const short* lk = lds_k[cur];
        const short* lv = lds_v[cur];

        #pragma unroll
        for (int ks = 0; ks < 2; ++ks)
            #pragma unroll
            for (int nt = 0; nt < 4; ++nt) {
                int cc = (ks * 4 + l4) ^ swz;
                bf16x8 kf = *(const bf16x8*)&lk[(nt * 16 + l15) * DH + cc * 8];
                sacc[nt] = __builtin_amdgcn_mfma_f32_16x16x32_bf16(qf[ks], kf, sacc[nt], 0, 0, 0);
            }

        // max-free softmax; P -> per-wave LDS (swizzled), per-lane l partials
        #pragma unroll
        for (int r = 0; r < 4; ++r) {
            const int prow = l4 * 4 + r;
            const int rsw = prow & 7;
            #pragma unroll
            for (int nt = 0; nt < 4; ++nt) {
                float pv = __builtin_amdgcn_exp2f(sacc[nt][r]);
                l_part[r] += pv;
                int pc = (nt * 2 + (l15 >> 3)) ^ rsw;     // swizzled 8-short chunk
                pw[prow * 64 + pc * 8 + (l15 & 7)] = f2b(pv);
            }
        }

        // O += P @ V
        #pragma unroll
        for (int ks = 0; ks < 2; ++ks) {
            int cc = (ks * 4 + l4) ^ swz;
            bf16x8 pf = *(const bf16x8*)&pw[l15 * 64 + cc * 8];
            #pragma unroll
            for (int dt = 0; dt < 4; ++dt) {
                bf16x8 vf = *(const bf16x8*)&lv[(dt * 16 + l15) * DH + cc * 8];
                o_acc[dt] = __builtin_amdgcn_mfma_f32_16x16x32_bf16(pf, vf, o_acc[dt], 0, 0, 0);
            }
        }

        // single barrier per tile: (a) all waves done reading buf[cur] before
        // it's restaged in iter kt+1; (b) implicit vmcnt(0) drain completes
        // stage(kt+1) AFTER a full tile of compute hid its latency.
        __syncthreads();
    }

    // l reduction across the 16-lane row groups
    #pragma unroll
    for (int r = 0; r < 4; ++r) {
        float s = l_part[r];
        #pragma unroll
        for (int m = 1; m < 16; m <<= 1) s += __shfl_xor(s, m, 64);
        l_part[r] = s;
    }

    #pragma unroll
    for (int r = 0; r < 4; ++r) {
        float inv = 1.0f / l_part[r];
        float* op = Ob + (size_t)(q0 + wave * 16 + l4 * 4 + r) * DH + l15;
        #pragma unroll
        for (int dt = 0; dt < 4; ++dt) op[dt * 16] = o_acc[dt][r] * inv;
    }
}

extern "C" void kernel_launch(void* const* d_in, const int* in_sizes, int n_in,
                              void* d_out, int out_size, void* d_ws, size_t ws_size,
                              hipStream_t stream) {
    const float* Q    = (const float*)d_in[0];
    const float* K    = (const float*)d_in[1];
    const float* V    = (const float*)d_in[2];
    const float* Bias = (const float*)d_in[3];
    float* O          = (float*)d_out;

    short* Kb = (short*)d_ws;                    // 8 MB
    short* Vt = Kb + (size_t)BHN * SEQ * DH;     // 8 MB

    prep_kv<<<dim3(BHN * 32), dim3(256), 0, stream>>>(K, V, Kb, Vt);
    mha_main<<<dim3(BHN * 32), dim3(256), 0, stream>>>(Q, Bias, Kb, Vt, O);
}